// Round 5
// baseline (538.767 us; speedup 1.0000x reference)
//
#include <hip/hip_runtime.h>
#include <hip/hip_fp16.h>

typedef short v8s __attribute__((ext_vector_type(8)));
typedef float v4f __attribute__((ext_vector_type(4)));
typedef float v2f __attribute__((ext_vector_type(2)));

#define NSP 32768
#define ZOFF 8192            // fallback: zp dword offset
#define XSTR 2056
#define FSTR 34              // fallback Fb stride
#define F2STR 33             // new p2 Fb stride (odd -> rotate banks)

// new-path ws byte offsets
#define WS_ZP_B   65536ull
#define WS_ATT_B  16842752ull        // 64K + 16MB
#define WS_V_B    50397184ull        // + 32MB att region
#define WS_NEED   184614912ull       // + 128MB v region

__device__ __forceinline__ unsigned short f2bf(float f) {
  union { float f; unsigned u; } v; v.f = f;
  unsigned r = v.u + 0x7fffu + ((v.u >> 16) & 1u);
  return (unsigned short)(r >> 16);
}
__device__ __forceinline__ unsigned pk(float a, float b) {
  return (unsigned)f2bf(a) | ((unsigned)f2bf(b) << 16);
}
__device__ __forceinline__ unsigned pkh(float a, float b) {
  union { __half2 h; unsigned u; } c; c.h = __floats2half2_rn(a, b); return c.u;
}
__device__ __forceinline__ float2 uph(unsigned u) {
  union { unsigned u; __half2 h; } c; c.u = u; return __half22float2(c.h);
}

union UF8 { v8s v; unsigned u[4]; uint4 q; };

// k-map convention used CONSISTENTLY for every A and B fragment (errors cancel):
// frag element j of lane (i16 + 16*g) <-> k = 16*(j>>2) + 4*g + (j&3)

__global__ __launch_bounds__(512) void prep_kernel(
    const float* __restrict__ Wk, const float* __restrict__ bk,
    const float* __restrict__ Wq, const float* __restrict__ bq,
    const float* __restrict__ Wv, unsigned* __restrict__ ws) {
  __shared__ float sWk[4096], sWq[4096], sWv[4096], sbk[64], sbq[64];
  for (int i = threadIdx.x; i < 4096; i += 512) { sWk[i] = Wk[i]; sWq[i] = Wq[i]; sWv[i] = Wv[i]; }
  if (threadIdx.x < 64) { sbk[threadIdx.x] = bk[threadIdx.x]; sbq[threadIdx.x] = bq[threadIdx.x]; }
  __syncthreads();
  for (int task = threadIdx.x; task < 18 * 64; task += 512) {
    int f = task >> 6, lane = task & 63;
    int i16 = lane & 15, g = lane >> 4;
    unsigned short e[8];
    #pragma unroll
    for (int j = 0; j < 8; ++j) {
      int k = (((j >> 2) << 4) + 4 * g + (j & 3));
      float acc = 0.f;
      if (f < 8) {
        int row = ((f >> 1) << 4) + i16;
        int cc  = ((f & 1) << 5) + k;
        for (int a = 0; a < 64; ++a) acc += sWk[a * 64 + row] * sWq[a * 64 + cc];
      } else if (f < 10) {
        int c = ((f - 8) << 5) + k;
        if (i16 == 0)      { for (int a = 0; a < 64; ++a) acc += sWk[a * 64 + c] * sbq[a]; }
        else if (i16 == 1) { for (int a = 0; a < 64; ++a) acc += sbk[a] * sWq[a * 64 + c]; }
      } else {
        int c  = (((f - 10) >> 1) << 4) + i16;
        int cp = (((f - 10) & 1) << 5) + k;
        acc = sWv[c * 64 + cp];
      }
      e[j] = f2bf(acc);
    }
    unsigned* dst = ws + (size_t)(f * 64 + lane) * 4;
    dst[0] = e[0] | ((unsigned)e[1] << 16);
    dst[1] = e[2] | ((unsigned)e[3] << 16);
    dst[2] = e[4] | ((unsigned)e[5] << 16);
    dst[3] = e[6] | ((unsigned)e[7] << 16);
  }
  if (threadIdx.x == 0) {
    float beta = 0.f;
    for (int a = 0; a < 64; ++a) beta += sbk[a] * sbq[a];
    ((float*)ws)[18 * 256] = beta;
  }
}

#define S2L 0.18033688011112042f  /* (1/8) * log2(e) */

#define DECODE_GRID() \
  int bid = (int)blockIdx.x; \
  int b = bid & 1, dc = (bid >> 1) & 3, h = bid >> 3; \
  const int d0 = dc << 3; \
  const size_t base0 = (size_t)b * 33554432 + h * 32;

#define DECODE512() \
  int bid = (int)blockIdx.x; \
  int b = bid & 1, dcc = (bid >> 1) & 7, h = bid >> 4; \
  const int d0 = dcc << 2; \
  const size_t base0 = (size_t)b * 33554432 + h * 32;

#define STAGE_DEFS() \
  const int w2 = tid & 15; \
  const int rp0 = tid >> 4; \
  v2f sA[16], sB[16]; \
  auto issueRegs = [&](int d) { \
    const float* xp = x + base0 + (size_t)d * 1024; \
    _Pragma("unroll") \
    for (int i = 0; i < 16; ++i) { \
      int rp = (i << 5) + rp0; \
      const float* r0 = xp + (size_t)(2 * rp) * NSP + 2 * w2; \
      sA[i] = *(const v2f*)r0; \
      sB[i] = *(const v2f*)(r0 + NSP); \
    } \
  }; \
  auto writeLds = [&]() { \
    _Pragma("unroll") \
    for (int i = 0; i < 16; ++i) { \
      int rp = (i << 5) + rp0; \
      int t = rp >> 5, c = (rp & 31) << 1; \
      int off = (t << 7) + (((c << 1)) ^ ((t & 7) << 4)); \
      *(unsigned*)(&Xbuf[(2 * w2) * XSTR + off])     = pk(sA[i].x, sB[i].x); \
      *(unsigned*)(&Xbuf[(2 * w2 + 1) * XSTR + off]) = pk(sA[i].y, sB[i].y); \
    } \
  };

#define LOADX_DEF() \
  auto loadX = [&](int loc, v8s fX[2]) { \
    const unsigned char* bp = &Xbuf[loc * XSTR + (i16 << 7)]; \
    const int sw = (i16 & 7) << 4; \
    _Pragma("unroll") \
    for (int kc = 0; kc < 2; ++kc) { \
      union { v8s v; unsigned long long dd[2]; } u; \
      int o = (kc << 6) + (g << 3); \
      u.dd[0] = *(const unsigned long long*)(bp + (o ^ sw)); \
      u.dd[1] = *(const unsigned long long*)(bp + ((o + 32) ^ sw)); \
      fX[kc] = u.v; \
    } \
  };

#define ATTOF_DEF() \
  auto attOf = [&](const v8s fX[2]) -> v4f { \
    v4f accW[4]; \
    _Pragma("unroll") \
    for (int tr = 0; tr < 4; ++tr) { \
      v4f a = {0.f, 0.f, 0.f, 0.f}; \
      a = __builtin_amdgcn_mfma_f32_16x16x32_bf16(fM[tr][0], fX[0], a, 0, 0, 0); \
      a = __builtin_amdgcn_mfma_f32_16x16x32_bf16(fM[tr][1], fX[1], a, 0, 0, 0); \
      accW[tr] = a; \
    } \
    v4f au = {0.f, 0.f, 0.f, 0.f}; \
    au = __builtin_amdgcn_mfma_f32_16x16x32_bf16(fUR[0], fX[0], au, 0, 0, 0); \
    au = __builtin_amdgcn_mfma_f32_16x16x32_bf16(fUR[1], fX[1], au, 0, 0, 0); \
    float a1v = au[0] + beta; \
    float a2v = au[1]; \
    float a2s = __shfl(a2v, i16); \
    v4f att; \
    _Pragma("unroll") \
    for (int j = 0; j < 4; ++j) att[j] = __shfl(a1v, 4 * g + j) + a2s; \
    _Pragma("unroll") \
    for (int kc = 0; kc < 2; ++kc) { \
      UF8 w; \
      w.u[0] = pk(accW[2 * kc][0], accW[2 * kc][1]); \
      w.u[1] = pk(accW[2 * kc][2], accW[2 * kc][3]); \
      w.u[2] = pk(accW[2 * kc + 1][0], accW[2 * kc + 1][1]); \
      w.u[3] = pk(accW[2 * kc + 1][2], accW[2 * kc + 1][3]); \
      att = __builtin_amdgcn_mfma_f32_16x16x32_bf16(fX[kc], w.v, att, 0, 0, 0); \
    } \
    return att; \
  };

// ================== NEW PATH ==================
// p1: att (f16, pre-scaled) + v (bf16 frags) + Z-partials. LDS = Xbuf only.
__global__ __launch_bounds__(512, 4) void p1_attv(
    const float* __restrict__ x, const float* __restrict__ bv,
    const unsigned* __restrict__ ws, float* __restrict__ zp,
    unsigned* __restrict__ attw, unsigned* __restrict__ vw) {
  __shared__ __align__(16) unsigned char Xbuf[32 * XSTR];
  const int tid = (int)threadIdx.x;
  const int lane = tid & 63, wv = tid >> 6;
  const int i16 = lane & 15, g = lane >> 4;
  DECODE512();

  v8s fM[4][2], fUR[2], fWv[4][2];
  {
    const uint4* W4 = (const uint4*)ws;
    #pragma unroll
    for (int f = 0; f < 8; ++f) { UF8 u; u.q = W4[f * 64 + lane]; fM[f >> 1][f & 1] = u.v; }
    #pragma unroll
    for (int f = 0; f < 2; ++f) { UF8 u; u.q = W4[(8 + f) * 64 + lane]; fUR[f] = u.v; }
    #pragma unroll
    for (int f = 0; f < 8; ++f) { UF8 u; u.q = W4[(10 + f) * 64 + lane]; fWv[f >> 1][f & 1] = u.v; }
  }
  const float beta = ((const float*)ws)[4608];
  float bvv[4];
  #pragma unroll
  for (int tn = 0; tn < 4; ++tn) bvv[tn] = bv[i16 + 16 * tn];

  STAGE_DEFS();
  LOADX_DEF();
  ATTOF_DEF();

  float Z[4][4] = {};
  issueRegs(d0);
  for (int ii = 0; ii < 4; ++ii) {
    __syncthreads();
    writeLds();
    if (ii < 3) issueRegs(d0 + ii + 1);
    __syncthreads();
    #pragma unroll
    for (int l = 0; l < 4; ++l) {
      const int w = 4 * wv + l;
      const size_t ls = (size_t)(bid * 4 + ii) * 32 + w;
      v8s fX[2]; loadX(w, fX);
      v4f att = attOf(fX);
      float s0 = att[0] * S2L, s1 = att[1] * S2L, s2 = att[2] * S2L, s3 = att[3] * S2L;
      Z[l][0] += exp2f(s0); Z[l][1] += exp2f(s1);
      Z[l][2] += exp2f(s2); Z[l][3] += exp2f(s3);
      uint2 av; av.x = pkh(s0, s1); av.y = pkh(s2, s3);
      *(uint2*)(attw + ls * 128 + lane * 2) = av;
      // v = X~ @ Wv~  (store exactly the B-fragment dwords pass2 needs)
      uint4 o0, o1;
      {
        v4f a;
        a = (v4f){bvv[0], bvv[0], bvv[0], bvv[0]};
        a = __builtin_amdgcn_mfma_f32_16x16x32_bf16(fX[0], fWv[0][0], a, 0, 0, 0);
        a = __builtin_amdgcn_mfma_f32_16x16x32_bf16(fX[1], fWv[0][1], a, 0, 0, 0);
        o0.x = pk(a[0], a[1]); o0.y = pk(a[2], a[3]);
        a = (v4f){bvv[1], bvv[1], bvv[1], bvv[1]};
        a = __builtin_amdgcn_mfma_f32_16x16x32_bf16(fX[0], fWv[1][0], a, 0, 0, 0);
        a = __builtin_amdgcn_mfma_f32_16x16x32_bf16(fX[1], fWv[1][1], a, 0, 0, 0);
        o0.z = pk(a[0], a[1]); o0.w = pk(a[2], a[3]);
        a = (v4f){bvv[2], bvv[2], bvv[2], bvv[2]};
        a = __builtin_amdgcn_mfma_f32_16x16x32_bf16(fX[0], fWv[2][0], a, 0, 0, 0);
        a = __builtin_amdgcn_mfma_f32_16x16x32_bf16(fX[1], fWv[2][1], a, 0, 0, 0);
        o1.x = pk(a[0], a[1]); o1.y = pk(a[2], a[3]);
        a = (v4f){bvv[3], bvv[3], bvv[3], bvv[3]};
        a = __builtin_amdgcn_mfma_f32_16x16x32_bf16(fX[0], fWv[3][0], a, 0, 0, 0);
        a = __builtin_amdgcn_mfma_f32_16x16x32_bf16(fX[1], fWv[3][1], a, 0, 0, 0);
        o1.z = pk(a[0], a[1]); o1.w = pk(a[2], a[3]);
      }
      uint4* vp = (uint4*)vw + ls * 128 + lane * 2;
      vp[0] = o0; vp[1] = o1;
    }
  }
  const int locg0 = b * 1024 + h * 32 + 4 * wv;
  #pragma unroll
  for (int l = 0; l < 4; ++l)
    #pragma unroll
    for (int j = 0; j < 4; ++j)
      zp[(((size_t)dcc * 2048 + locg0 + l) << 8) + (4 * g + j) * 16 + i16] = Z[l][j];
}

// p2: exp + PV + transpose + full-line out. LDS = Fb only -> 2 blocks/CU.
__global__ __launch_bounds__(512, 4) void p2_feat(
    const float* __restrict__ zp, const unsigned* __restrict__ attw,
    const unsigned* __restrict__ vw, float* __restrict__ out) {
  __shared__ float Fb[512 * F2STR];
  const int tid = (int)threadIdx.x;
  const int lane = tid & 63, wv = tid >> 6;
  const int i16 = lane & 15, g = lane >> 4;
  DECODE512();

  const int locg0 = b * 1024 + h * 32 + 4 * wv;
  float iZ[4][4];
  #pragma unroll
  for (int l = 0; l < 4; ++l)
    #pragma unroll
    for (int j = 0; j < 4; ++j) {
      float s = 0.f;
      #pragma unroll
      for (int c2 = 0; c2 < 8; ++c2)
        s += zp[(((size_t)c2 * 2048 + locg0 + l) << 8) + (4 * g + j) * 16 + i16];
      iZ[l][j] = 1.f / s;
    }

  auto storeHalf = [&](int half, int d) {
    float* op = out + base0 + (size_t)d * 1024 + ((size_t)half << 5) * NSP;
    const int w4 = tid & 7, rr = tid >> 3;
    #pragma unroll
    for (int ro = 0; ro < 8; ++ro) {
      int r = (ro << 6) + rr;
      int s = r >> 5, ci = r & 31;
      int col = (w4 << 2) ^ (((r >> 7) & 1) << 4);
      int bse = r * F2STR + col;
      float4 val;
      val.x = Fb[bse]; val.y = Fb[bse + 1]; val.z = Fb[bse + 2]; val.w = Fb[bse + 3];
      *(float4*)(op + (size_t)(s * 64 + ci) * NSP + (w4 << 2)) = val;
    }
  };

  for (int ii = 0; ii < 4; ++ii) {
    const int d = d0 + ii;
    uint2 ar[4]; uint4 va[4], vb[4];
    #pragma unroll
    for (int l = 0; l < 4; ++l) {
      const size_t ls = (size_t)(bid * 4 + ii) * 32 + 4 * wv + l;
      ar[l] = *(const uint2*)(attw + ls * 128 + lane * 2);
      const uint4* vp = (const uint4*)vw + ls * 128 + lane * 2;
      va[l] = vp[0]; vb[l] = vp[1];
    }
    unsigned fPu[4][2];
    __syncthreads();                      // prev storeHalf(1) done
    #pragma unroll
    for (int l = 0; l < 4; ++l) {
      const int w = 4 * wv + l;
      float2 f01 = uph(ar[l].x), f23 = uph(ar[l].y);
      float p0 = exp2f(f01.x) * iZ[l][0], p1 = exp2f(f01.y) * iZ[l][1];
      float p2 = exp2f(f23.x) * iZ[l][2], p3 = exp2f(f23.y) * iZ[l][3];
      fPu[l][0] = pk(p0, p1); fPu[l][1] = pk(p2, p3);
      UF8 fP; fP.u[0] = fPu[l][0]; fP.u[1] = fPu[l][1]; fP.u[2] = 0; fP.u[3] = 0;
      #pragma unroll
      for (int tn = 0; tn < 2; ++tn) {
        UF8 fV;
        fV.u[0] = tn == 0 ? va[l].x : va[l].z;
        fV.u[1] = tn == 0 ? va[l].y : va[l].w;
        fV.u[2] = 0; fV.u[3] = 0;
        v4f ft = {0.f, 0.f, 0.f, 0.f};
        ft = __builtin_amdgcn_mfma_f32_16x16x32_bf16(fP.v, fV.v, ft, 0, 0, 0);
        #pragma unroll
        for (int j = 0; j < 4; ++j) {
          int r = (4 * g + j) * 32 + i16 + 16 * tn;
          Fb[r * F2STR + (w ^ ((g & 1) << 4))] = ft[j];
        }
      }
    }
    __syncthreads();
    storeHalf(0, d);
    __syncthreads();
    #pragma unroll
    for (int l = 0; l < 4; ++l) {
      const int w = 4 * wv + l;
      UF8 fP; fP.u[0] = fPu[l][0]; fP.u[1] = fPu[l][1]; fP.u[2] = 0; fP.u[3] = 0;
      #pragma unroll
      for (int tn = 0; tn < 2; ++tn) {
        UF8 fV;
        fV.u[0] = tn == 0 ? vb[l].x : vb[l].z;
        fV.u[1] = tn == 0 ? vb[l].y : vb[l].w;
        fV.u[2] = 0; fV.u[3] = 0;
        v4f ft = {0.f, 0.f, 0.f, 0.f};
        ft = __builtin_amdgcn_mfma_f32_16x16x32_bf16(fP.v, fV.v, ft, 0, 0, 0);
        #pragma unroll
        for (int j = 0; j < 4; ++j) {
          int r = (4 * g + j) * 32 + i16 + 16 * tn;
          Fb[r * F2STR + (w ^ ((g & 1) << 4))] = ft[j];
        }
      }
    }
    __syncthreads();
    storeHalf(1, d);
  }
}

// ================== FALLBACK (R4, proven) ==================
__global__ __launch_bounds__(512) void pass1_z(
    const float* __restrict__ x, const unsigned* __restrict__ ws,
    float* __restrict__ zp) {
  __shared__ __align__(16) unsigned char Xbuf[32 * XSTR];
  const int tid = (int)threadIdx.x;
  const int lane = tid & 63, wv = tid >> 6;
  const int i16 = lane & 15, g = lane >> 4;
  DECODE_GRID();
  v8s fM[4][2], fUR[2];
  {
    const uint4* W4 = (const uint4*)ws;
    #pragma unroll
    for (int f = 0; f < 8; ++f) { UF8 u; u.q = W4[f * 64 + lane]; fM[f >> 1][f & 1] = u.v; }
    #pragma unroll
    for (int f = 0; f < 2; ++f) { UF8 u; u.q = W4[(8 + f) * 64 + lane]; fUR[f] = u.v; }
  }
  const float beta = ((const float*)ws)[4608];
  STAGE_DEFS(); LOADX_DEF(); ATTOF_DEF();
  float Z[4][4] = {};
  issueRegs(d0);
  for (int ii = 0; ii < 8; ++ii) {
    __syncthreads();
    writeLds();
    if (ii < 7) issueRegs(d0 + ii + 1);
    __syncthreads();
    #pragma unroll
    for (int l = 0; l < 4; ++l) {
      v8s fX[2]; loadX(4 * wv + l, fX);
      v4f att = attOf(fX);
      #pragma unroll
      for (int j = 0; j < 4; ++j) Z[l][j] += exp2f(att[j] * S2L);
    }
  }
  const int locg = b * 1024 + h * 32 + 4 * wv;
  #pragma unroll
  for (int l = 0; l < 4; ++l)
    #pragma unroll
    for (int j = 0; j < 4; ++j)
      zp[(((size_t)dc * 2048 + locg + l) << 8) + (4 * g + j) * 16 + i16] = Z[l][j];
}

__global__ __launch_bounds__(512) void pass2_out(
    const float* __restrict__ x, const float* __restrict__ bv,
    const unsigned* __restrict__ ws, const float* __restrict__ zp,
    float* __restrict__ out) {
  __shared__ __align__(16) unsigned char Xbuf[32 * XSTR];
  __shared__ float Fb[512 * FSTR];
  const int tid = (int)threadIdx.x;
  const int lane = tid & 63, wv = tid >> 6;
  const int i16 = lane & 15, g = lane >> 4;
  DECODE_GRID();
  v8s fM[4][2], fUR[2], fWv[4][2];
  {
    const uint4* W4 = (const uint4*)ws;
    #pragma unroll
    for (int f = 0; f < 8; ++f) { UF8 u; u.q = W4[f * 64 + lane]; fM[f >> 1][f & 1] = u.v; }
    #pragma unroll
    for (int f = 0; f < 2; ++f) { UF8 u; u.q = W4[(8 + f) * 64 + lane]; fUR[f] = u.v; }
    #pragma unroll
    for (int f = 0; f < 8; ++f) { UF8 u; u.q = W4[(10 + f) * 64 + lane]; fWv[f >> 1][f & 1] = u.v; }
  }
  const float beta = ((const float*)ws)[4608];
  float bvv[4];
  #pragma unroll
  for (int tn = 0; tn < 4; ++tn) bvv[tn] = bv[i16 + 16 * tn];
  const int locg = b * 1024 + h * 32 + 4 * wv;
  float iZ[4][4];
  #pragma unroll
  for (int l = 0; l < 4; ++l)
    #pragma unroll
    for (int j = 0; j < 4; ++j) {
      float s = 0.f;
      #pragma unroll
      for (int c2 = 0; c2 < 4; ++c2)
        s += zp[(((size_t)c2 * 2048 + locg + l) << 8) + (4 * g + j) * 16 + i16];
      iZ[l][j] = 1.f / s;
    }
  STAGE_DEFS(); LOADX_DEF(); ATTOF_DEF();
  auto storeHalf = [&](int half, int d) {
    float* op = out + base0 + (size_t)d * 1024 + ((size_t)half << 5) * NSP;
    const int w4 = tid & 7, rr = tid >> 3;
    #pragma unroll
    for (int ro = 0; ro < 8; ++ro) {
      int r = (ro << 6) + rr;
      int s = r >> 5, ci = r & 31;
      int v = ((r >> 7) & 1) << 2;
      int bse = r * FSTR + ((w4 << 2) ^ v);
      float4 val;
      val.x = Fb[bse]; val.y = Fb[bse + 1]; val.z = Fb[bse + 2]; val.w = Fb[bse + 3];
      *(float4*)(op + (size_t)(s * 64 + ci) * NSP + (w4 << 2)) = val;
    }
  };
  issueRegs(d0 + 7);
  for (int ii = 0; ii < 8; ++ii) {
    const int d = d0 + 7 - ii;
    __syncthreads();
    writeLds();
    if (ii < 7) issueRegs(d - 1);
    __syncthreads();
    unsigned fPs[4][2];
    #pragma unroll
    for (int l = 0; l < 4; ++l) {
      const int w = 4 * wv + l;
      v8s fX[2]; loadX(w, fX);
      v4f att = attOf(fX);
      float p[4];
      #pragma unroll
      for (int j = 0; j < 4; ++j) p[j] = exp2f(att[j] * S2L) * iZ[l][j];
      fPs[l][0] = pk(p[0], p[1]); fPs[l][1] = pk(p[2], p[3]);
      #pragma unroll
      for (int tn = 0; tn < 2; ++tn) {
        v4f a = {bvv[tn], bvv[tn], bvv[tn], bvv[tn]};
        a = __builtin_amdgcn_mfma_f32_16x16x32_bf16(fX[0], fWv[tn][0], a, 0, 0, 0);
        a = __builtin_amdgcn_mfma_f32_16x16x32_bf16(fX[1], fWv[tn][1], a, 0, 0, 0);
        UF8 fV; fV.u[0] = pk(a[0], a[1]); fV.u[1] = pk(a[2], a[3]); fV.u[2] = 0; fV.u[3] = 0;
        UF8 fP; fP.u[0] = fPs[l][0]; fP.u[1] = fPs[l][1]; fP.u[2] = 0; fP.u[3] = 0;
        v4f ft = {0.f, 0.f, 0.f, 0.f};
        ft = __builtin_amdgcn_mfma_f32_16x16x32_bf16(fP.v, fV.v, ft, 0, 0, 0);
        #pragma unroll
        for (int j = 0; j < 4; ++j) {
          int r = (4 * g + j) * 32 + i16 + 16 * tn;
          Fb[r * FSTR + (w ^ (((r >> 7) & 1) << 2))] = ft[j];
        }
      }
    }
    __syncthreads();
    storeHalf(0, d);
    __syncthreads();
    #pragma unroll
    for (int l = 0; l < 4; ++l) {
      const int w = 4 * wv + l;
      v8s fX[2]; loadX(w, fX);
      #pragma unroll
      for (int tn = 2; tn < 4; ++tn) {
        v4f a = {bvv[tn], bvv[tn], bvv[tn], bvv[tn]};
        a = __builtin_amdgcn_mfma_f32_16x16x32_bf16(fX[0], fWv[tn][0], a, 0, 0, 0);
        a = __builtin_amdgcn_mfma_f32_16x16x32_bf16(fX[1], fWv[tn][1], a, 0, 0, 0);
        UF8 fV; fV.u[0] = pk(a[0], a[1]); fV.u[1] = pk(a[2], a[3]); fV.u[2] = 0; fV.u[3] = 0;
        UF8 fP; fP.u[0] = fPs[l][0]; fP.u[1] = fPs[l][1]; fP.u[2] = 0; fP.u[3] = 0;
        v4f ft = {0.f, 0.f, 0.f, 0.f};
        ft = __builtin_amdgcn_mfma_f32_16x16x32_bf16(fP.v, fV.v, ft, 0, 0, 0);
        #pragma unroll
        for (int j = 0; j < 4; ++j) {
          int r = (4 * g + j) * 32 + i16 + 16 * (tn - 2);
          Fb[r * FSTR + (w ^ (((r >> 7) & 1) << 2))] = ft[j];
        }
      }
    }
    __syncthreads();
    storeHalf(1, d);
  }
}

extern "C" void kernel_launch(void* const* d_in, const int* in_sizes, int n_in,
                              void* d_out, int out_size, void* d_ws, size_t ws_size,
                              hipStream_t stream) {
  const float* x  = (const float*)d_in[0];
  const float* Wk = (const float*)d_in[1];
  const float* bk = (const float*)d_in[2];
  const float* Wq = (const float*)d_in[3];
  const float* bq = (const float*)d_in[4];
  const float* Wv = (const float*)d_in[5];
  const float* bv = (const float*)d_in[6];
  float* out = (float*)d_out;
  unsigned* ws = (unsigned*)d_ws;

  prep_kernel<<<1, 512, 0, stream>>>(Wk, bk, Wq, bq, Wv, ws);
  if (ws_size >= WS_NEED) {
    float*    zp   = (float*)((char*)d_ws + WS_ZP_B);
    unsigned* attw = (unsigned*)((char*)d_ws + WS_ATT_B);
    unsigned* vw   = (unsigned*)((char*)d_ws + WS_V_B);
    p1_attv<<<512, 512, 0, stream>>>(x, bv, ws, zp, attw, vw);
    p2_feat<<<512, 512, 0, stream>>>(zp, attw, vw, out);
  } else {
    float* zp = (float*)d_ws + ZOFF;
    pass1_z<<<256, 512, 0, stream>>>(x, ws, zp);
    pass2_out<<<256, 512, 0, stream>>>(x, bv, ws, zp, out);
  }
}